// Round 1
// baseline (1766.917 us; speedup 1.0000x reference)
//
#include <hip/hip_runtime.h>
#include <math.h>

#define WSZ 8
#define SSZ 4
#define NHD 6
#define CHD 16
#define CCH 96
#define NPT 64
#define HH  256
#define WWI 256
#define QSCALE 0.25f
#define NEGV (-1e9f)
#define EPSV 1e-5f

// ---------------------------------------------------------------------------
// Kernel A: shifted-window blind-spot attention + residual + LN + proj.
// One block per window (8192 windows), 384 threads = 6 waves = 6 heads.
// Writes post-proj tensor to `out` in the final (window-reversed, unshifted)
// (B,H,W,C) layout.
// ---------------------------------------------------------------------------
__global__ __launch_bounds__(384, 3)
void attn_kernel(const float* __restrict__ q_g, const float* __restrict__ k_g,
                 const float* __restrict__ v_g, const float* __restrict__ rpb,
                 const float* __restrict__ ng,  const float* __restrict__ nb,
                 const float* __restrict__ pw,  const float* __restrict__ pb,
                 float* __restrict__ out)
{
    __shared__ __align__(16) float sK[NHD * NPT * CHD];   // [head][tok][ch]
    __shared__ __align__(16) float sV[NHD * NPT * CHD];
    __shared__ float sX[NPT * 101];                       // 101: gcd(101%32=5,32)=1 -> conflict-free
    __shared__ float sMu[NPT], sRs[NPT];
    __shared__ int   sRid[NPT];

    const int n  = blockIdx.x;
    const int b  = n >> 10;
    const int nw = n & 1023;
    const int wh = nw >> 5, ww = nw & 31;
    const int t  = threadIdx.x;
    const int head = __builtin_amdgcn_readfirstlane(t >> 6);  // wave-uniform
    const int p  = t & 63;

    const long long img_base = (long long)b * (HH * WWI * CCH);

    // ---- stage K,V: 1536 float4 each, 8 float4/thread total -------------
    #pragma unroll
    for (int i = 0; i < 4; ++i) {
        int idx4 = t + i * 384;             // [0,1536)
        int pp   = idx4 / 24;               // token in window
        int cc   = (idx4 % 24) * 4;         // channel
        int r = pp >> 3, c2 = pp & 7;
        int gh = (wh * 8 + r  + SSZ) & 255;
        int gw = (ww * 8 + c2 + SSZ) & 255;
        long long ga = img_base + (long long)(gh * WWI + gw) * CCH + cc;
        float4 kv = *(const float4*)(k_g + ga);
        float4 vv = *(const float4*)(v_g + ga);
        int hd = cc >> 4, ch = cc & 15;
        *(float4*)(&sK[hd * (NPT * CHD) + pp * CHD + ch]) = kv;
        *(float4*)(&sV[hd * (NPT * CHD) + pp * CHD + ch]) = vv;
    }
    // ---- region ids (shifted-grid coords, per Swin mask construction) ----
    if (t < 64) {
        int r = t >> 3, c2 = t & 7;
        int hh2 = wh * 8 + r;
        int ww2 = ww * 8 + c2;
        int rh = (hh2 < HH - WSZ) ? 0 : ((hh2 < HH - SSZ) ? 1 : 2);
        int rw = (ww2 < WWI - WSZ) ? 0 : ((ww2 < WWI - SSZ) ? 1 : 2);
        sRid[t] = rh * 3 + rw;
    }

    // ---- own q row (scaled) ---------------------------------------------
    const int r1 = p >> 3, c1 = p & 7;
    float4 qr0, qr1, qr2, qr3;
    {
        int gh = (wh * 8 + r1 + SSZ) & 255;
        int gw = (ww * 8 + c1 + SSZ) & 255;
        long long ga = img_base + (long long)(gh * WWI + gw) * CCH + head * CHD;
        qr0 = *(const float4*)(q_g + ga);
        qr1 = *(const float4*)(q_g + ga + 4);
        qr2 = *(const float4*)(q_g + ga + 8);
        qr3 = *(const float4*)(q_g + ga + 12);
        qr0.x *= QSCALE; qr0.y *= QSCALE; qr0.z *= QSCALE; qr0.w *= QSCALE;
        qr1.x *= QSCALE; qr1.y *= QSCALE; qr1.z *= QSCALE; qr1.w *= QSCALE;
        qr2.x *= QSCALE; qr2.y *= QSCALE; qr2.z *= QSCALE; qr2.w *= QSCALE;
        qr3.x *= QSCALE; qr3.y *= QSCALE; qr3.z *= QSCALE; qr3.w *= QSCALE;
    }
    __syncthreads();

    // ---- scores + bias + mask -------------------------------------------
    float s[64];
    const int rid_i = sRid[p];
    const float* biasbase = rpb + ((r1 + 7) * 15 + (c1 + 7)) * NHD + head;
    const float* kh = &sK[head * (NPT * CHD)];
    #pragma unroll
    for (int j = 0; j < 64; ++j) {
        const float4 k0 = *(const float4*)(kh + j * 16);
        const float4 k1 = *(const float4*)(kh + j * 16 + 4);
        const float4 k2 = *(const float4*)(kh + j * 16 + 8);
        const float4 k3 = *(const float4*)(kh + j * 16 + 12);
        float d0 = qr0.x * k0.x + qr0.y * k0.y + qr0.z * k0.z + qr0.w * k0.w;
        float d1 = qr1.x * k1.x + qr1.y * k1.y + qr1.z * k1.z + qr1.w * k1.w;
        float d2 = qr2.x * k2.x + qr2.y * k2.y + qr2.z * k2.z + qr2.w * k2.w;
        float d3 = qr3.x * k3.x + qr3.y * k3.y + qr3.z * k3.z + qr3.w * k3.w;
        int r2 = j >> 3, c2 = j & 7;
        float bias = biasbase[-(r2 * 15 + c2) * NHD];
        float msk = (sRid[j] != rid_i || j == p) ? NEGV : 0.0f;
        s[j] = (d0 + d1) + (d2 + d3) + bias + msk;
    }

    // ---- softmax (in-thread, tree max / tree sum) ------------------------
    float m8[8];
    #pragma unroll
    for (int j = 0; j < 8; ++j) m8[j] = s[j];
    #pragma unroll
    for (int j = 8; j < 64; ++j) m8[j & 7] = fmaxf(m8[j & 7], s[j]);
    float mx = fmaxf(fmaxf(fmaxf(m8[0], m8[1]), fmaxf(m8[2], m8[3])),
                     fmaxf(fmaxf(m8[4], m8[5]), fmaxf(m8[6], m8[7])));
    float l8[8];
    #pragma unroll
    for (int j = 0; j < 8; ++j) { s[j] = __expf(s[j] - mx); l8[j] = s[j]; }
    #pragma unroll
    for (int j = 8; j < 64; ++j) { s[j] = __expf(s[j] - mx); l8[j & 7] += s[j]; }
    float l = ((l8[0] + l8[1]) + (l8[2] + l8[3])) + ((l8[4] + l8[5]) + (l8[6] + l8[7]));
    float invl = 1.0f / l;

    // ---- PV --------------------------------------------------------------
    float4 a0 = {0,0,0,0}, a1 = {0,0,0,0}, a2 = {0,0,0,0}, a3 = {0,0,0,0};
    const float* vh = &sV[head * (NPT * CHD)];
    #pragma unroll
    for (int j = 0; j < 64; ++j) {
        float pj = s[j];
        const float4 v0 = *(const float4*)(vh + j * 16);
        const float4 v1 = *(const float4*)(vh + j * 16 + 4);
        const float4 v2 = *(const float4*)(vh + j * 16 + 8);
        const float4 v3 = *(const float4*)(vh + j * 16 + 12);
        a0.x += pj * v0.x; a0.y += pj * v0.y; a0.z += pj * v0.z; a0.w += pj * v0.w;
        a1.x += pj * v1.x; a1.y += pj * v1.y; a1.z += pj * v1.z; a1.w += pj * v1.w;
        a2.x += pj * v2.x; a2.y += pj * v2.y; a2.z += pj * v2.z; a2.w += pj * v2.w;
        a3.x += pj * v3.x; a3.y += pj * v3.y; a3.z += pj * v3.z; a3.w += pj * v3.w;
    }
    // normalize + residual (q already scaled) -> sX[token][head*16+ch]
    {
        float* xr = &sX[p * 101 + head * CHD];
        xr[0]  = a0.x * invl + qr0.x; xr[1]  = a0.y * invl + qr0.y;
        xr[2]  = a0.z * invl + qr0.z; xr[3]  = a0.w * invl + qr0.w;
        xr[4]  = a1.x * invl + qr1.x; xr[5]  = a1.y * invl + qr1.y;
        xr[6]  = a1.z * invl + qr1.z; xr[7]  = a1.w * invl + qr1.w;
        xr[8]  = a2.x * invl + qr2.x; xr[9]  = a2.y * invl + qr2.y;
        xr[10] = a2.z * invl + qr2.z; xr[11] = a2.w * invl + qr2.w;
        xr[12] = a3.x * invl + qr3.x; xr[13] = a3.y * invl + qr3.y;
        xr[14] = a3.z * invl + qr3.z; xr[15] = a3.w * invl + qr3.w;
    }
    __syncthreads();

    // ---- LN stats (wave 0) ----------------------------------------------
    if (t < 64) {
        float sum = 0.f, sq = 0.f;
        for (int c = 0; c < 96; ++c) {
            float x = sX[t * 101 + c];
            sum += x; sq += x * x;
        }
        float mu  = sum * (1.0f / 96.0f);
        float var = sq * (1.0f / 96.0f) - mu * mu;
        sMu[t] = mu;
        sRs[t] = 1.0f / sqrtf(var + EPSV);
    }
    __syncthreads();

    // ---- normalize in place (thread covers its 16 channels of token p) ---
    {
        float mu = sMu[p], rs = sRs[p];
        #pragma unroll
        for (int i = 0; i < 16; ++i) {
            int c = head * CHD + i;
            float x = sX[p * 101 + c];
            sX[p * 101 + c] = (x - mu) * rs * ng[c] + nb[c];
        }
    }
    __syncthreads();

    // ---- proj: thread (head,p) computes outputs o = head*16..+15 ---------
    {
        float acc[16];
        #pragma unroll
        for (int i = 0; i < 16; ++i) acc[i] = 0.f;
        const float* xrow  = &sX[p * 101];
        const float* wbase = pw + head * 16 * 96;   // wave-uniform -> scalar loads
        #pragma unroll 4
        for (int c = 0; c < 96; ++c) {
            float xv = xrow[c];
            #pragma unroll
            for (int i = 0; i < 16; ++i) acc[i] += xv * wbase[i * 96 + c];
        }
        int gh = (wh * 8 + r1 + SSZ) & 255;
        int gw = (ww * 8 + c1 + SSZ) & 255;
        float* op = out + img_base + (long long)(gh * WWI + gw) * CCH + head * 16;
        #pragma unroll
        for (int i = 0; i < 16; i += 4) {
            float4 v;
            v.x = acc[i + 0] + pb[head * 16 + i + 0];
            v.y = acc[i + 1] + pb[head * 16 + i + 1];
            v.z = acc[i + 2] + pb[head * 16 + i + 2];
            v.w = acc[i + 3] + pb[head * 16 + i + 3];
            *(float4*)(op + i) = v;
        }
    }
}

// ---------------------------------------------------------------------------
// Kernel B: per-token MLP with pre-LN, in-place on `io`:
//   io = io + fc2(gelu(fc1(LN2(io))))
// 64 tokens per block, 256 threads (4 waves x 24-output chunks).
// ---------------------------------------------------------------------------
__global__ __launch_bounds__(256, 3)
void mlp_kernel(float* __restrict__ io,
                const float* __restrict__ g2, const float* __restrict__ b2,
                const float* __restrict__ w1, const float* __restrict__ bb1,
                const float* __restrict__ w2, const float* __restrict__ bb2)
{
    __shared__ float sX[64 * 101];
    __shared__ float sH[64 * 97];
    __shared__ float sMu[64], sRs[64];

    const int t = threadIdx.x;
    const long long base = (long long)blockIdx.x * (64 * 96);

    // stage 64 tokens x 96 ch (contiguous 24.6 KB)
    #pragma unroll
    for (int i = 0; i < 6; ++i) {
        int idx4 = t + i * 256;                 // [0,1536)
        int pp = idx4 / 24, cc = (idx4 % 24) * 4;
        float4 x = *(const float4*)(io + base + (long long)idx4 * 4);
        float* d = &sX[pp * 101 + cc];
        d[0] = x.x; d[1] = x.y; d[2] = x.z; d[3] = x.w;
    }
    __syncthreads();

    if (t < 64) {
        float sum = 0.f, sq = 0.f;
        for (int c = 0; c < 96; ++c) {
            float x = sX[t * 101 + c];
            sum += x; sq += x * x;
        }
        float mu  = sum * (1.0f / 96.0f);
        float var = sq * (1.0f / 96.0f) - mu * mu;
        sMu[t] = mu;
        sRs[t] = 1.0f / sqrtf(var + EPSV);
    }
    __syncthreads();

    const int grp = __builtin_amdgcn_readfirstlane(t >> 6);  // 0..3, wave-uniform
    const int p   = t & 63;
    const float mu = sMu[p], rs = sRs[p];

    // fc1 + GELU -> sH
    {
        float acc[24];
        #pragma unroll
        for (int i = 0; i < 24; ++i) acc[i] = 0.f;
        const float* xrow = &sX[p * 101];
        const float* w1b  = w1 + grp * 24 * 96;
        #pragma unroll 4
        for (int c = 0; c < 96; ++c) {
            float xv = (xrow[c] - mu) * rs * g2[c] + b2[c];
            #pragma unroll
            for (int i = 0; i < 24; ++i) acc[i] += xv * w1b[i * 96 + c];
        }
        #pragma unroll
        for (int i = 0; i < 24; ++i) {
            float h = acc[i] + bb1[grp * 24 + i];
            h = 0.5f * h * (1.0f + erff(h * 0.70710678118654752f));
            sH[p * 97 + grp * 24 + i] = h;
        }
    }
    __syncthreads();

    // fc2 + residual -> global (in-place safe: all reads are from LDS)
    {
        float acc[24];
        #pragma unroll
        for (int i = 0; i < 24; ++i) acc[i] = 0.f;
        const float* hrow = &sH[p * 97];
        const float* w2b  = w2 + grp * 24 * 96;
        #pragma unroll 4
        for (int o = 0; o < 96; ++o) {
            float hv = hrow[o];
            #pragma unroll
            for (int i = 0; i < 24; ++i) acc[i] += hv * w2b[i * 96 + o];
        }
        #pragma unroll
        for (int i = 0; i < 24; i += 4) {
            int o = grp * 24 + i;
            float4 v;
            v.x = sX[p * 101 + o + 0] + acc[i + 0] + bb2[o + 0];
            v.y = sX[p * 101 + o + 1] + acc[i + 1] + bb2[o + 1];
            v.z = sX[p * 101 + o + 2] + acc[i + 2] + bb2[o + 2];
            v.w = sX[p * 101 + o + 3] + acc[i + 3] + bb2[o + 3];
            *(float4*)(io + base + p * 96 + o) = v;
        }
    }
}

extern "C" void kernel_launch(void* const* d_in, const int* in_sizes, int n_in,
                              void* d_out, int out_size, void* d_ws, size_t ws_size,
                              hipStream_t stream) {
    (void)in_sizes; (void)n_in; (void)out_size; (void)d_ws; (void)ws_size;
    const float* q_g  = (const float*)d_in[0];
    const float* k_g  = (const float*)d_in[1];
    const float* v_g  = (const float*)d_in[2];
    const float* rpb  = (const float*)d_in[3];
    const float* ng   = (const float*)d_in[4];
    const float* nb   = (const float*)d_in[5];
    const float* pw   = (const float*)d_in[6];
    const float* pb   = (const float*)d_in[7];
    const float* g2   = (const float*)d_in[8];
    const float* b2   = (const float*)d_in[9];
    const float* w1   = (const float*)d_in[10];
    const float* bb1  = (const float*)d_in[11];
    const float* w2   = (const float*)d_in[12];
    const float* bb2  = (const float*)d_in[13];
    float* out = (float*)d_out;

    attn_kernel<<<dim3(8192), dim3(384), 0, stream>>>(q_g, k_g, v_g, rpb, ng, nb, pw, pb, out);
    mlp_kernel<<<dim3(8192), dim3(256), 0, stream>>>(out, g2, b2, w1, bb1, w2, bb2);
}